// Round 9
// baseline (414.895 us; speedup 1.0000x reference)
//
#include <hip/hip_runtime.h>
#include <hip/hip_bf16.h>

// Mapper: 4 per-word GEMM layers with LN+LeakyReLU between.
// Round 9: barrier-free, LDS-free GEMM. Five rounds of barrier-phased LDS
// staging all pinned at ~1600+ cyc/K-step with every pipe idle (convoy +
// conservative vmcnt from conditional loads). New structure: each wave owns a
// 64x64 output tile entirely in registers; A loaded as contiguous 16B k-chunks,
// B as 8 strided dwords/frag converted via v_cvt_pk_bf16_f32. No __shared__,
// no barriers, fully unconditional load stream (tail peeled), 2-slot unroll.

typedef unsigned short u16;
typedef __attribute__((ext_vector_type(8))) short bf16x8;
typedef __attribute__((ext_vector_type(4))) float f32x4;

constexpr int CB = 256;      // batch
constexpr int CW = 20;       // words
constexpr int CDIN = 1024;
constexpr int CDOUT = 1024;
constexpr int CH = 1280;
constexpr float CEPS = 1e-5f;
constexpr float CSLOPE = 0.01f;

__device__ __forceinline__ u16 f2bf(float f) {
    union { float f; unsigned u; } v; v.f = f;
    unsigned r = v.u + 0x7fffu + ((v.u >> 16) & 1u);
    return (u16)(r >> 16);
}
// packed pair via HW v_cvt_pk_bf16_f32
__device__ __forceinline__ unsigned pk2(float a, float b) {
    __hip_bfloat162 h = __float22bfloat162_rn(float2{a, b});
    union { __hip_bfloat162 h; unsigned u; } v; v.h = h;
    return v.u;
}
__device__ __forceinline__ bf16x8 pack8(float4 a, float4 b) {
    union { unsigned u[4]; bf16x8 v; } r;
    r.u[0] = pk2(a.x, a.y); r.u[1] = pk2(a.z, a.w);
    r.u[2] = pk2(b.x, b.y); r.u[3] = pk2(b.z, b.w);
    return r.v;
}

// ---------------------------------------------------------------------------
// GEMM: out[b, w, n] = sum_k A[b, w, k] * Bw[w, k, n] + bias[w, n]
// A: bf16 (u16) or fp32 (AF32), row (b*CW+w), K-contiguous.  Bw: fp32 [W][K][N].
// Tile: BM=128, BN=128, BK=32. 4 waves (2x2), wave-tile 64x64 = 4x4 MFMA
// 16x16x32 = 16 MFMA/wave/step. All operands in registers; no LDS/barriers.
// Grid: 2 * (N/128) * CW blocks, XCD-swizzled, mb fastest (weight L2 reuse).
// ---------------------------------------------------------------------------
template <int K, int N, bool AF32>
__global__ __launch_bounds__(256, 2) void gemm_kernel(
    const void* __restrict__ Aptr, const float* __restrict__ Bw,
    const float* __restrict__ bias, float* __restrict__ Out)
{
    constexpr int NB  = N / 128;
    constexpr int NK  = K / 32;          // 32 or 40 (even)
    static_assert(NK % 2 == 0 && NK >= 4, "NK must be even");
    constexpr int NWG = 2 * NB * CW;
    constexpr int CPX = NWG / 8;

    const int t   = threadIdx.x;
    const int bid = blockIdx.x;
    const int logical = (bid & 7) * CPX + (bid >> 3);
    const int mb = logical & 1;
    const int nb = (logical >> 1) % NB;
    const int w  = logical / (2 * NB);

    const int m0g = mb * 128;
    const int n0g = nb * 128;

    const int lane = t & 63;
    const int wid  = t >> 6;
    const int wrm  = (wid >> 1) * 64;    // wave row offset in block tile
    const int wcn  = (wid & 1) * 64;     // wave col offset in block tile
    const int lrow = lane & 15;
    const int kg   = lane >> 4;          // 0..3

    // A fragment pointers: frag i -> row m0g+wrm+i*16+lrow, k-chunk kg*8 (16B)
    const int r0 = m0g + wrm + lrow;
    const u16* a0p = (const u16*)Aptr + ((size_t)(r0)      * CW + w) * K + kg * 8;
    const u16* a1p = (const u16*)Aptr + ((size_t)(r0 + 16) * CW + w) * K + kg * 8;
    const u16* a2p = (const u16*)Aptr + ((size_t)(r0 + 32) * CW + w) * K + kg * 8;
    const u16* a3p = (const u16*)Aptr + ((size_t)(r0 + 48) * CW + w) * K + kg * 8;
    const float* a0pf = (const float*)Aptr + ((size_t)(r0)      * CW + w) * K + kg * 8;
    const float* a1pf = (const float*)Aptr + ((size_t)(r0 + 16) * CW + w) * K + kg * 8;
    const float* a2pf = (const float*)Aptr + ((size_t)(r0 + 32) * CW + w) * K + kg * 8;
    const float* a3pf = (const float*)Aptr + ((size_t)(r0 + 48) * CW + w) * K + kg * 8;

    // B fragment lane pointers: frag j -> n = n0g+wcn+j*16+lrow, k = kg*8+m
    const float* bb  = Bw + (size_t)w * K * N + (size_t)(kg * 8) * N + (n0g + wcn + lrow);
    const float* bp0 = bb;
    const float* bp1 = bb + 16;
    const float* bp2 = bb + 32;
    const float* bp3 = bb + 48;

    f32x4 acc[4][4];
    #pragma unroll
    for (int i = 0; i < 4; ++i)
        #pragma unroll
        for (int j = 0; j < 4; ++j)
            acc[i][j] = (f32x4){0.f, 0.f, 0.f, 0.f};

    // register slots (all statically named)
    uint4  ar_A_0, ar_A_1, ar_A_2, ar_A_3;
    uint4  ar_B_0, ar_B_1, ar_B_2, ar_B_3;
    float4 af_A_0a, af_A_0b, af_A_1a, af_A_1b, af_A_2a, af_A_2b, af_A_3a, af_A_3b;
    float4 af_B_0a, af_B_0b, af_B_1a, af_B_1b, af_B_2a, af_B_2b, af_B_3a, af_B_3b;
    float b_A_0_0, b_A_0_1, b_A_0_2, b_A_0_3, b_A_0_4, b_A_0_5, b_A_0_6, b_A_0_7;
    float b_A_1_0, b_A_1_1, b_A_1_2, b_A_1_3, b_A_1_4, b_A_1_5, b_A_1_6, b_A_1_7;
    float b_A_2_0, b_A_2_1, b_A_2_2, b_A_2_3, b_A_2_4, b_A_2_5, b_A_2_6, b_A_2_7;
    float b_A_3_0, b_A_3_1, b_A_3_2, b_A_3_3, b_A_3_4, b_A_3_5, b_A_3_6, b_A_3_7;
    float b_B_0_0, b_B_0_1, b_B_0_2, b_B_0_3, b_B_0_4, b_B_0_5, b_B_0_6, b_B_0_7;
    float b_B_1_0, b_B_1_1, b_B_1_2, b_B_1_3, b_B_1_4, b_B_1_5, b_B_1_6, b_B_1_7;
    float b_B_2_0, b_B_2_1, b_B_2_2, b_B_2_3, b_B_2_4, b_B_2_5, b_B_2_6, b_B_2_7;
    float b_B_3_0, b_B_3_1, b_B_3_2, b_B_3_3, b_B_3_4, b_B_3_5, b_B_3_6, b_B_3_7;

#define LOADB1(k0, SL, J)                                                     \
    do {                                                                      \
        const float* _pB = bp##J + (size_t)(k0) * N;                          \
        b_##SL##_##J##_0 = _pB[0];                                            \
        b_##SL##_##J##_1 = _pB[(size_t)1 * N];                                \
        b_##SL##_##J##_2 = _pB[(size_t)2 * N];                                \
        b_##SL##_##J##_3 = _pB[(size_t)3 * N];                                \
        b_##SL##_##J##_4 = _pB[(size_t)4 * N];                                \
        b_##SL##_##J##_5 = _pB[(size_t)5 * N];                                \
        b_##SL##_##J##_6 = _pB[(size_t)6 * N];                                \
        b_##SL##_##J##_7 = _pB[(size_t)7 * N];                                \
    } while (0)

#define LOADB(k0, SL)                                                         \
    do {                                                                      \
        LOADB1(k0, SL, 0); LOADB1(k0, SL, 1);                                 \
        LOADB1(k0, SL, 2); LOADB1(k0, SL, 3);                                 \
    } while (0)

#define LOADA(k0, SL)                                                         \
    do {                                                                      \
        if constexpr (AF32) {                                                 \
            af_##SL##_0a = *reinterpret_cast<const float4*>(a0pf + (k0));     \
            af_##SL##_0b = *reinterpret_cast<const float4*>(a0pf + (k0) + 4); \
            af_##SL##_1a = *reinterpret_cast<const float4*>(a1pf + (k0));     \
            af_##SL##_1b = *reinterpret_cast<const float4*>(a1pf + (k0) + 4); \
            af_##SL##_2a = *reinterpret_cast<const float4*>(a2pf + (k0));     \
            af_##SL##_2b = *reinterpret_cast<const float4*>(a2pf + (k0) + 4); \
            af_##SL##_3a = *reinterpret_cast<const float4*>(a3pf + (k0));     \
            af_##SL##_3b = *reinterpret_cast<const float4*>(a3pf + (k0) + 4); \
        } else {                                                              \
            ar_##SL##_0 = *reinterpret_cast<const uint4*>(a0p + (k0));        \
            ar_##SL##_1 = *reinterpret_cast<const uint4*>(a1p + (k0));        \
            ar_##SL##_2 = *reinterpret_cast<const uint4*>(a2p + (k0));        \
            ar_##SL##_3 = *reinterpret_cast<const uint4*>(a3p + (k0));        \
        }                                                                     \
    } while (0)

#define COMPUTE(SL)                                                           \
    do {                                                                      \
        bf16x8 a0f, a1f, a2f, a3f;                                            \
        if constexpr (AF32) {                                                 \
            a0f = pack8(af_##SL##_0a, af_##SL##_0b);                          \
            a1f = pack8(af_##SL##_1a, af_##SL##_1b);                          \
            a2f = pack8(af_##SL##_2a, af_##SL##_2b);                          \
            a3f = pack8(af_##SL##_3a, af_##SL##_3b);                          \
        } else {                                                              \
            a0f = __builtin_bit_cast(bf16x8, ar_##SL##_0);                    \
            a1f = __builtin_bit_cast(bf16x8, ar_##SL##_1);                    \
            a2f = __builtin_bit_cast(bf16x8, ar_##SL##_2);                    \
            a3f = __builtin_bit_cast(bf16x8, ar_##SL##_3);                    \
        }                                                                     \
        bf16x8 bf0 = pack8(                                                   \
            float4{b_##SL##_0_0, b_##SL##_0_1, b_##SL##_0_2, b_##SL##_0_3},   \
            float4{b_##SL##_0_4, b_##SL##_0_5, b_##SL##_0_6, b_##SL##_0_7});  \
        bf16x8 bf1 = pack8(                                                   \
            float4{b_##SL##_1_0, b_##SL##_1_1, b_##SL##_1_2, b_##SL##_1_3},   \
            float4{b_##SL##_1_4, b_##SL##_1_5, b_##SL##_1_6, b_##SL##_1_7});  \
        bf16x8 bf2 = pack8(                                                   \
            float4{b_##SL##_2_0, b_##SL##_2_1, b_##SL##_2_2, b_##SL##_2_3},   \
            float4{b_##SL##_2_4, b_##SL##_2_5, b_##SL##_2_6, b_##SL##_2_7});  \
        bf16x8 bf3 = pack8(                                                   \
            float4{b_##SL##_3_0, b_##SL##_3_1, b_##SL##_3_2, b_##SL##_3_3},   \
            float4{b_##SL##_3_4, b_##SL##_3_5, b_##SL##_3_6, b_##SL##_3_7});  \
        acc[0][0] = __builtin_amdgcn_mfma_f32_16x16x32_bf16(a0f, bf0, acc[0][0], 0, 0, 0); \
        acc[1][0] = __builtin_amdgcn_mfma_f32_16x16x32_bf16(a1f, bf0, acc[1][0], 0, 0, 0); \
        acc[2][0] = __builtin_amdgcn_mfma_f32_16x16x32_bf16(a2f, bf0, acc[2][0], 0, 0, 0); \
        acc[3][0] = __builtin_amdgcn_mfma_f32_16x16x32_bf16(a3f, bf0, acc[3][0], 0, 0, 0); \
        acc[0][1] = __builtin_amdgcn_mfma_f32_16x16x32_bf16(a0f, bf1, acc[0][1], 0, 0, 0); \
        acc[1][1] = __builtin_amdgcn_mfma_f32_16x16x32_bf16(a1f, bf1, acc[1][1], 0, 0, 0); \
        acc[2][1] = __builtin_amdgcn_mfma_f32_16x16x32_bf16(a2f, bf1, acc[2][1], 0, 0, 0); \
        acc[3][1] = __builtin_amdgcn_mfma_f32_16x16x32_bf16(a3f, bf1, acc[3][1], 0, 0, 0); \
        acc[0][2] = __builtin_amdgcn_mfma_f32_16x16x32_bf16(a0f, bf2, acc[0][2], 0, 0, 0); \
        acc[1][2] = __builtin_amdgcn_mfma_f32_16x16x32_bf16(a1f, bf2, acc[1][2], 0, 0, 0); \
        acc[2][2] = __builtin_amdgcn_mfma_f32_16x16x32_bf16(a2f, bf2, acc[2][2], 0, 0, 0); \
        acc[3][2] = __builtin_amdgcn_mfma_f32_16x16x32_bf16(a3f, bf2, acc[3][2], 0, 0, 0); \
        acc[0][3] = __builtin_amdgcn_mfma_f32_16x16x32_bf16(a0f, bf3, acc[0][3], 0, 0, 0); \
        acc[1][3] = __builtin_amdgcn_mfma_f32_16x16x32_bf16(a1f, bf3, acc[1][3], 0, 0, 0); \
        acc[2][3] = __builtin_amdgcn_mfma_f32_16x16x32_bf16(a2f, bf3, acc[2][3], 0, 0, 0); \
        acc[3][3] = __builtin_amdgcn_mfma_f32_16x16x32_bf16(a3f, bf3, acc[3][3], 0, 0, 0); \
    } while (0)

    // software pipeline, 2-slot, tail peeled — every load unconditional
    LOADB(0, A); LOADA(0, A);
    for (int ks = 0; ks < NK - 2; ks += 2) {
        LOADB((ks + 1) * 32, B); LOADA((ks + 1) * 32, B);
        COMPUTE(A);
        LOADB((ks + 2) * 32, A); LOADA((ks + 2) * 32, A);
        COMPUTE(B);
    }
    LOADB((NK - 1) * 32, B); LOADA((NK - 1) * 32, B);
    COMPUTE(A);
    COMPUTE(B);

    // epilogue: + bias, store fp32
    const int rb = (lane >> 4) * 4;
    #pragma unroll
    for (int j = 0; j < 4; ++j) {
        const int gn = n0g + wcn + j * 16 + lrow;
        const float bv = bias[(size_t)w * N + gn];
        #pragma unroll
        for (int i = 0; i < 4; ++i) {
            const int gm = m0g + wrm + i * 16 + rb;
            #pragma unroll
            for (int r = 0; r < 4; ++r) {
                Out[((size_t)(gm + r) * CW + w) * N + gn] = acc[i][j][r] + bv;
            }
        }
    }
#undef LOADB1
#undef LOADB
#undef LOADA
#undef COMPUTE
}

// ---------------------------------------------------------------------------
// LayerNorm + LeakyReLU over last dim (H=1280), writes bf16.
// ---------------------------------------------------------------------------
__global__ __launch_bounds__(320) void ln_lrelu_kernel(
    const float* __restrict__ h, const float* __restrict__ g,
    const float* __restrict__ bta, u16* __restrict__ out)
{
    const int row = blockIdx.x;          // b*CW + w
    const int w = row % CW;
    const int t = threadIdx.x;

    const float4 v = reinterpret_cast<const float4*>(h + (size_t)row * CH)[t];
    float s  = v.x + v.y + v.z + v.w;
    float sq = v.x * v.x + v.y * v.y + v.z * v.z + v.w * v.w;
    #pragma unroll
    for (int o = 32; o > 0; o >>= 1) {
        s  += __shfl_down(s, o, 64);
        sq += __shfl_down(sq, o, 64);
    }
    __shared__ float ss[5], sg[5];
    const int lane = t & 63, wv = t >> 6;
    if (lane == 0) { ss[wv] = s; sg[wv] = sq; }
    __syncthreads();
    float S = 0.f, Q = 0.f;
    #pragma unroll
    for (int i = 0; i < 5; ++i) { S += ss[i]; Q += sg[i]; }
    const float mean = S * (1.0f / CH);
    const float var  = Q * (1.0f / CH) - mean * mean;
    const float rstd = rsqrtf(var + CEPS);

    const float4 gg = reinterpret_cast<const float4*>(g   + (size_t)w * CH)[t];
    const float4 bb = reinterpret_cast<const float4*>(bta + (size_t)w * CH)[t];
    float4 y;
    y.x = (v.x - mean) * rstd * gg.x + bb.x;
    y.y = (v.y - mean) * rstd * gg.y + bb.y;
    y.z = (v.z - mean) * rstd * gg.z + bb.z;
    y.w = (v.w - mean) * rstd * gg.w + bb.w;
    y.x = y.x >= 0.f ? y.x : CSLOPE * y.x;
    y.y = y.y >= 0.f ? y.y : CSLOPE * y.y;
    y.z = y.z >= 0.f ? y.z : CSLOPE * y.z;
    y.w = y.w >= 0.f ? y.w : CSLOPE * y.w;
    ushort4 o4;
    o4.x = f2bf(y.x); o4.y = f2bf(y.y); o4.z = f2bf(y.z); o4.w = f2bf(y.w);
    reinterpret_cast<ushort4*>(out + (size_t)row * CH)[t] = o4;
}

extern "C" void kernel_launch(void* const* d_in, const int* in_sizes, int n_in,
                              void* d_out, int out_size, void* d_ws, size_t ws_size,
                              hipStream_t stream)
{
    const float* embs = (const float*)d_in[0];
    const float* W1  = (const float*)d_in[1];
    const float* b1  = (const float*)d_in[2];
    const float* g1  = (const float*)d_in[3];
    const float* bn1 = (const float*)d_in[4];
    const float* W2  = (const float*)d_in[5];
    const float* b2  = (const float*)d_in[6];
    const float* g2  = (const float*)d_in[7];
    const float* bn2 = (const float*)d_in[8];
    const float* W3  = (const float*)d_in[9];
    const float* b3  = (const float*)d_in[10];
    const float* g3  = (const float*)d_in[11];
    const float* bn3 = (const float*)d_in[12];
    const float* W4  = (const float*)d_in[13];
    const float* b4  = (const float*)d_in[14];

    char* ws = (char*)d_ws;
    float* h_raw = (float*)ws;                               // B*W*H*4  = 26,214,400
    u16*   a_bf  = (u16*)(ws + 26214400);                    // B*W*H*2  = 13,107,200

    // Layer 1: [256x1024] @ [1024x1280], A = embs fp32 (cvt at consume)
    gemm_kernel<CDIN, CH, true><<<2 * (CH / 128) * CW, 256, 0, stream>>>(embs, W1, b1, h_raw);
    ln_lrelu_kernel<<<CB * CW, 320, 0, stream>>>(h_raw, g1, bn1, a_bf);
    // Layer 2: [256x1280] @ [1280x1280]
    gemm_kernel<CH, CH, false><<<2 * (CH / 128) * CW, 256, 0, stream>>>(a_bf, W2, b2, h_raw);
    ln_lrelu_kernel<<<CB * CW, 320, 0, stream>>>(h_raw, g2, bn2, a_bf);
    // Layer 3: [256x1280] @ [1280x1280]
    gemm_kernel<CH, CH, false><<<2 * (CH / 128) * CW, 256, 0, stream>>>(a_bf, W3, b3, h_raw);
    ln_lrelu_kernel<<<CB * CW, 320, 0, stream>>>(h_raw, g3, bn3, a_bf);
    // Layer 4: [256x1280] @ [1280x1024] -> d_out (fp32)
    gemm_kernel<CH, CDOUT, false><<<2 * (CDOUT / 128) * CW, 256, 0, stream>>>(a_bf, W4, b4, (float*)d_out);
}

// Round 10
// 322.670 us; speedup vs baseline: 1.2858x; 1.2858x over previous
//
#include <hip/hip_runtime.h>
#include <hip/hip_bf16.h>

// Mapper: 4 per-word GEMM layers with LN+LeakyReLU between.
// Round 10: R8 structure (BM=128,BN=64,BK=32; A global->reg depth-2, B reg
// depth-4 -> LDS; raw lgkm-only barriers) with the K-loop FULLY UNROLLED so
// every load guard constant-folds away. Theory: runtime-conditional loads
// prevented counted vmcnt waits (compiler fell back to conservative drains),
// which is why depth-2/depth-4 prefetch never changed the counters.
// Also __launch_bounds__(256,4) to double resident waves.

typedef unsigned short u16;
typedef __attribute__((ext_vector_type(8))) short bf16x8;
typedef __attribute__((ext_vector_type(4))) float f32x4;

constexpr int CB = 256;      // batch
constexpr int CW = 20;       // words
constexpr int CDIN = 1024;
constexpr int CDOUT = 1024;
constexpr int CH = 1280;
constexpr float CEPS = 1e-5f;
constexpr float CSLOPE = 0.01f;

__device__ __forceinline__ u16 f2bf(float f) {
    union { float f; unsigned u; } v; v.f = f;
    unsigned r = v.u + 0x7fffu + ((v.u >> 16) & 1u);
    return (u16)(r >> 16);
}
// packed pair via HW v_cvt_pk_bf16_f32
__device__ __forceinline__ unsigned pk2(float a, float b) {
    __hip_bfloat162 h = __float22bfloat162_rn(float2{a, b});
    union { __hip_bfloat162 h; unsigned u; } v; v.h = h;
    return v.u;
}
__device__ __forceinline__ bf16x8 pack8(float4 a, float4 b) {
    union { unsigned u[4]; bf16x8 v; } r;
    r.u[0] = pk2(a.x, a.y); r.u[1] = pk2(a.z, a.w);
    r.u[2] = pk2(b.x, b.y); r.u[3] = pk2(b.z, b.w);
    return r.v;
}

// Workgroup barrier without the vmcnt(0) drain (LDS-visibility only).
__device__ __forceinline__ void bar_keep_vmem() {
    asm volatile("s_waitcnt lgkmcnt(0)" ::: "memory");
    __builtin_amdgcn_s_barrier();
    __builtin_amdgcn_sched_barrier(0);
}

// ---------------------------------------------------------------------------
// GEMM: out[b, w, n] = sum_k A[b, w, k] * Bw[w, k, n] + bias[w, n]
// A: bf16 (u16) or fp32 (AF32), row (b*CW+w), K-contiguous.  Bw: fp32 [W][K][N].
// Tile: BM=128, BN=64, BK=32. 4 waves stacked in M, wave-tile 32x64
// = 2(m) x 4(n) MFMA 16x16x32 = 8 MFMA/wave/step.
// B: 4 register slots -> cvt_pk -> LDS [n][k] stride 40 u16, double-buffered.
// A: 2 parity register slots, global->reg direct (L2-served via XCD swizzle).
// K-loop fully unrolled: all load guards are compile-time constants.
// Grid: 2 * (N/64) * CW blocks, XCD-swizzled, mb fastest.
// ---------------------------------------------------------------------------
template <int K, int N, bool AF32>
__global__ __launch_bounds__(256, 4) void gemm_kernel(
    const void* __restrict__ Aptr, const float* __restrict__ Bw,
    const float* __restrict__ bias, float* __restrict__ Out)
{
    constexpr int NB  = N / 64;
    constexpr int NK  = K / 32;          // 32 or 40 (divisible by 4)
    static_assert(NK % 4 == 0 && NK >= 8, "NK must be multiple of 4");
    constexpr int NWG = 2 * NB * CW;
    constexpr int CPX = NWG / 8;

    __shared__ u16 Bs[2][64 * 40];

    const int t   = threadIdx.x;
    const int bid = blockIdx.x;
    const int logical = (bid & 7) * CPX + (bid >> 3);
    const int mb = logical & 1;
    const int nb = (logical >> 1) % NB;
    const int w  = logical / (2 * NB);

    const int m0g = mb * 128;
    const int n0g = nb * 64;

    const int lane = t & 63;
    const int wid  = t >> 6;
    const int lrow = lane & 15;
    const int kg   = lane >> 4;          // 0..3

    // A-fragment base pointers (16B contiguous k-chunks per lane).
    const int r0 = m0g + wid * 32 + lrow;
    const u16*   a0p  = (const u16*)Aptr   + ((size_t)r0 * CW + w) * K + kg * 8;
    const u16*   a1p  = (const u16*)Aptr   + ((size_t)(r0 + 16) * CW + w) * K + kg * 8;
    const float* a0pf = (const float*)Aptr + ((size_t)r0 * CW + w) * K + kg * 8;
    const float* a1pf = (const float*)Aptr + ((size_t)(r0 + 16) * CW + w) * K + kg * 8;

    // B staging: thread -> (n = t&63, k-rows wid*8 .. +7), dword stride N
    const int bn = t & 63;
    const float* bgp = Bw + (size_t)w * K * N + (size_t)wid * 8 * N + (n0g + bn);
    const int bwoff = bn * 40 + wid * 8;

    f32x4 acc[2][4];
    #pragma unroll
    for (int i = 0; i < 2; ++i)
        #pragma unroll
        for (int j = 0; j < 4; ++j)
            acc[i][j] = (f32x4){0.f, 0.f, 0.f, 0.f};

    // prefetch slots — static names only
    uint4  ar_A_0, ar_A_1, ar_B_0, ar_B_1;                 // bf16 A frags
    float4 af_A_0a, af_A_0b, af_A_1a, af_A_1b;             // fp32 A frags (L1)
    float4 af_B_0a, af_B_0b, af_B_1a, af_B_1b;
    float  b_s0_0, b_s0_1, b_s0_2, b_s0_3, b_s0_4, b_s0_5, b_s0_6, b_s0_7;
    float  b_s1_0, b_s1_1, b_s1_2, b_s1_3, b_s1_4, b_s1_5, b_s1_6, b_s1_7;
    float  b_s2_0, b_s2_1, b_s2_2, b_s2_3, b_s2_4, b_s2_5, b_s2_6, b_s2_7;
    float  b_s3_0, b_s3_1, b_s3_2, b_s3_3, b_s3_4, b_s3_5, b_s3_6, b_s3_7;

#define LOADAF(k0, SL)                                                        \
    do {                                                                      \
        if constexpr (AF32) {                                                 \
            af_##SL##_0a = *reinterpret_cast<const float4*>(a0pf + (k0));     \
            af_##SL##_0b = *reinterpret_cast<const float4*>(a0pf + (k0) + 4); \
            af_##SL##_1a = *reinterpret_cast<const float4*>(a1pf + (k0));     \
            af_##SL##_1b = *reinterpret_cast<const float4*>(a1pf + (k0) + 4); \
        } else {                                                              \
            ar_##SL##_0 = *reinterpret_cast<const uint4*>(a0p + (k0));        \
            ar_##SL##_1 = *reinterpret_cast<const uint4*>(a1p + (k0));        \
        }                                                                     \
    } while (0)

#define LOADB(k0, SL)                                                         \
    do {                                                                      \
        const float* _pB = bgp + (size_t)(k0) * N;                            \
        b_s##SL##_0 = _pB[0];               b_s##SL##_1 = _pB[(size_t)1 * N]; \
        b_s##SL##_2 = _pB[(size_t)2 * N];   b_s##SL##_3 = _pB[(size_t)3 * N]; \
        b_s##SL##_4 = _pB[(size_t)4 * N];   b_s##SL##_5 = _pB[(size_t)5 * N]; \
        b_s##SL##_6 = _pB[(size_t)6 * N];   b_s##SL##_7 = _pB[(size_t)7 * N]; \
    } while (0)

#define WRITEB(buf, SL)                                                       \
    do {                                                                      \
        uint4 q;                                                              \
        q.x = pk2(b_s##SL##_0, b_s##SL##_1);                                  \
        q.y = pk2(b_s##SL##_2, b_s##SL##_3);                                  \
        q.z = pk2(b_s##SL##_4, b_s##SL##_5);                                  \
        q.w = pk2(b_s##SL##_6, b_s##SL##_7);                                  \
        *reinterpret_cast<uint4*>(&Bs[buf][bwoff]) = q;                       \
    } while (0)

#define COMPUTE(buf, SL)                                                      \
    do {                                                                      \
        bf16x8 a0f, a1f;                                                      \
        if constexpr (AF32) {                                                 \
            a0f = pack8(af_##SL##_0a, af_##SL##_0b);                          \
            a1f = pack8(af_##SL##_1a, af_##SL##_1b);                          \
        } else {                                                              \
            a0f = __builtin_bit_cast(bf16x8, ar_##SL##_0);                    \
            a1f = __builtin_bit_cast(bf16x8, ar_##SL##_1);                    \
        }                                                                     \
        bf16x8 bf0 = *reinterpret_cast<const bf16x8*>(                        \
            &Bs[buf][(0 * 16 + lrow) * 40 + kg * 8]);                         \
        bf16x8 bf1 = *reinterpret_cast<const bf16x8*>(                        \
            &Bs[buf][(1 * 16 + lrow) * 40 + kg * 8]);                         \
        bf16x8 bf2 = *reinterpret_cast<const bf16x8*>(                        \
            &Bs[buf][(2 * 16 + lrow) * 40 + kg * 8]);                         \
        bf16x8 bf3 = *reinterpret_cast<const bf16x8*>(                        \
            &Bs[buf][(3 * 16 + lrow) * 40 + kg * 8]);                         \
        acc[0][0] = __builtin_amdgcn_mfma_f32_16x16x32_bf16(a0f, bf0, acc[0][0], 0, 0, 0); \
        acc[1][0] = __builtin_amdgcn_mfma_f32_16x16x32_bf16(a1f, bf0, acc[1][0], 0, 0, 0); \
        acc[0][1] = __builtin_amdgcn_mfma_f32_16x16x32_bf16(a0f, bf1, acc[0][1], 0, 0, 0); \
        acc[1][1] = __builtin_amdgcn_mfma_f32_16x16x32_bf16(a1f, bf1, acc[1][1], 0, 0, 0); \
        acc[0][2] = __builtin_amdgcn_mfma_f32_16x16x32_bf16(a0f, bf2, acc[0][2], 0, 0, 0); \
        acc[1][2] = __builtin_amdgcn_mfma_f32_16x16x32_bf16(a1f, bf2, acc[1][2], 0, 0, 0); \
        acc[0][3] = __builtin_amdgcn_mfma_f32_16x16x32_bf16(a0f, bf3, acc[0][3], 0, 0, 0); \
        acc[1][3] = __builtin_amdgcn_mfma_f32_16x16x32_bf16(a1f, bf3, acc[1][3], 0, 0, 0); \
    } while (0)

    // prologue: B slots <- steps 0..3; A slots <- steps 0,1; LDS buf0 <- 0
    LOADB(0 * 32, 0); LOADB(1 * 32, 1); LOADB(2 * 32, 2); LOADB(3 * 32, 3);
    LOADAF(0 * 32, A); LOADAF(1 * 32, B);
    WRITEB(0, 0);                        // counted vmcnt wait on slot-0 only
    bar_keep_vmem();

    // K-loop: FULLY UNROLLED so every `p+k < NK` guard is a compile-time
    // constant -> all loads unconditional in emitted code -> static issue
    // counts -> compiler emits counted s_waitcnt vmcnt(N), never drains.
    #pragma unroll
    for (int p = 0; p < NK; p += 4) {
        // q = p+0: consume buf0/slotA; stage slot1 -> buf1; refill slot0
        if (p + 4 < NK) LOADB((p + 4) * 32, 0);
        COMPUTE(0, A);
        if (p + 2 < NK) LOADAF((p + 2) * 32, A);
        if (p + 1 < NK) WRITEB(1, 1);
        bar_keep_vmem();

        // q = p+1: consume buf1/slotB; stage slot2 -> buf0; refill slot1
        if (p + 5 < NK) LOADB((p + 5) * 32, 1);
        COMPUTE(1, B);
        if (p + 3 < NK) LOADAF((p + 3) * 32, B);
        if (p + 2 < NK) WRITEB(0, 2);
        bar_keep_vmem();

        // q = p+2: consume buf0/slotA; stage slot3 -> buf1; refill slot2
        if (p + 6 < NK) LOADB((p + 6) * 32, 2);
        COMPUTE(0, A);
        if (p + 4 < NK) LOADAF((p + 4) * 32, A);
        if (p + 3 < NK) WRITEB(1, 3);
        bar_keep_vmem();

        // q = p+3: consume buf1/slotB; stage slot0 -> buf0; refill slot3
        if (p + 7 < NK) LOADB((p + 7) * 32, 3);
        COMPUTE(1, B);
        if (p + 5 < NK) LOADAF((p + 5) * 32, B);
        if (p + 4 < NK) WRITEB(0, 0);
        bar_keep_vmem();
    }

    // epilogue: + bias, store fp32
    const int rb = (lane >> 4) * 4;
    #pragma unroll
    for (int j = 0; j < 4; ++j) {
        const int gn = n0g + j * 16 + lrow;
        const float bv = bias[(size_t)w * N + gn];
        #pragma unroll
        for (int i = 0; i < 2; ++i) {
            const int gm = m0g + wid * 32 + i * 16 + rb;
            #pragma unroll
            for (int r = 0; r < 4; ++r) {
                Out[((size_t)(gm + r) * CW + w) * N + gn] = acc[i][j][r] + bv;
            }
        }
    }
#undef LOADAF
#undef LOADB
#undef WRITEB
#undef COMPUTE
}

// ---------------------------------------------------------------------------
// LayerNorm + LeakyReLU over last dim (H=1280), writes bf16.
// ---------------------------------------------------------------------------
__global__ __launch_bounds__(320) void ln_lrelu_kernel(
    const float* __restrict__ h, const float* __restrict__ g,
    const float* __restrict__ bta, u16* __restrict__ out)
{
    const int row = blockIdx.x;          // b*CW + w
    const int w = row % CW;
    const int t = threadIdx.x;

    const float4 v = reinterpret_cast<const float4*>(h + (size_t)row * CH)[t];
    float s  = v.x + v.y + v.z + v.w;
    float sq = v.x * v.x + v.y * v.y + v.z * v.z + v.w * v.w;
    #pragma unroll
    for (int o = 32; o > 0; o >>= 1) {
        s  += __shfl_down(s, o, 64);
        sq += __shfl_down(sq, o, 64);
    }
    __shared__ float ss[5], sg[5];
    const int lane = t & 63, wv = t >> 6;
    if (lane == 0) { ss[wv] = s; sg[wv] = sq; }
    __syncthreads();
    float S = 0.f, Q = 0.f;
    #pragma unroll
    for (int i = 0; i < 5; ++i) { S += ss[i]; Q += sg[i]; }
    const float mean = S * (1.0f / CH);
    const float var  = Q * (1.0f / CH) - mean * mean;
    const float rstd = rsqrtf(var + CEPS);

    const float4 gg = reinterpret_cast<const float4*>(g   + (size_t)w * CH)[t];
    const float4 bb = reinterpret_cast<const float4*>(bta + (size_t)w * CH)[t];
    float4 y;
    y.x = (v.x - mean) * rstd * gg.x + bb.x;
    y.y = (v.y - mean) * rstd * gg.y + bb.y;
    y.z = (v.z - mean) * rstd * gg.z + bb.z;
    y.w = (v.w - mean) * rstd * gg.w + bb.w;
    y.x = y.x >= 0.f ? y.x : CSLOPE * y.x;
    y.y = y.y >= 0.f ? y.y : CSLOPE * y.y;
    y.z = y.z >= 0.f ? y.z : CSLOPE * y.z;
    y.w = y.w >= 0.f ? y.w : CSLOPE * y.w;
    ushort4 o4;
    o4.x = f2bf(y.x); o4.y = f2bf(y.y); o4.z = f2bf(y.z); o4.w = f2bf(y.w);
    reinterpret_cast<ushort4*>(out + (size_t)row * CH)[t] = o4;
}

extern "C" void kernel_launch(void* const* d_in, const int* in_sizes, int n_in,
                              void* d_out, int out_size, void* d_ws, size_t ws_size,
                              hipStream_t stream)
{
    const float* embs = (const float*)d_in[0];
    const float* W1  = (const float*)d_in[1];
    const float* b1  = (const float*)d_in[2];
    const float* g1  = (const float*)d_in[3];
    const float* bn1 = (const float*)d_in[4];
    const float* W2  = (const float*)d_in[5];
    const float* b2  = (const float*)d_in[6];
    const float* g2  = (const float*)d_in[7];
    const float* bn2 = (const float*)d_in[8];
    const float* W3  = (const float*)d_in[9];
    const float* b3  = (const float*)d_in[10];
    const float* g3  = (const float*)d_in[11];
    const float* bn3 = (const float*)d_in[12];
    const float* W4  = (const float*)d_in[13];
    const float* b4  = (const float*)d_in[14];

    char* ws = (char*)d_ws;
    float* h_raw = (float*)ws;                               // B*W*H*4  = 26,214,400
    u16*   a_bf  = (u16*)(ws + 26214400);                    // B*W*H*2  = 13,107,200

    // Layer 1: [256x1024] @ [1024x1280], A = embs fp32 (cvt at consume)
    gemm_kernel<CDIN, CH, true><<<2 * (CH / 64) * CW, 256, 0, stream>>>(embs, W1, b1, h_raw);
    ln_lrelu_kernel<<<CB * CW, 320, 0, stream>>>(h_raw, g1, bn1, a_bf);
    // Layer 2: [256x1280] @ [1280x1280]
    gemm_kernel<CH, CH, false><<<2 * (CH / 64) * CW, 256, 0, stream>>>(a_bf, W2, b2, h_raw);
    ln_lrelu_kernel<<<CB * CW, 320, 0, stream>>>(h_raw, g2, bn2, a_bf);
    // Layer 3: [256x1280] @ [1280x1280]
    gemm_kernel<CH, CH, false><<<2 * (CH / 64) * CW, 256, 0, stream>>>(a_bf, W3, b3, h_raw);
    ln_lrelu_kernel<<<CB * CW, 320, 0, stream>>>(h_raw, g3, bn3, a_bf);
    // Layer 4: [256x1280] @ [1280x1024] -> d_out (fp32)
    gemm_kernel<CH, CDOUT, false><<<2 * (CDOUT / 64) * CW, 256, 0, stream>>>(a_bf, W4, b4, (float*)d_out);
}